// Round 1
// baseline (1616.372 us; speedup 1.0000x reference)
//
#include <hip/hip_runtime.h>

// SymmetricContraction (MACE-style), B=128, C=128, E=10, L=16.
// Algebraic collapse: out is a full contraction of U-tensors with rank-1
// products of per-(b,c) vectors; no big intermediates needed.
//   pairs p = b*128+c (16384), GEMM rows m: 0..767 = 1o (w=m>>8, q=m&255,
//   q=(x<<4)|v), 768..1023 = 0e (q=m-768=(w<<4)|x).
//   acc[m][p] = sum_{i,k} U3[m][i*K3+k] * x[p][i]*z3[p][k]  (+ U2 cols with z2)
//   out contribution = sum_m Q[p][q(m)] * acc[m][p],  Q[p][q]=x[p][q>>4]*x[p][q&15]
//   plus tiny U1 terms added in the epilogue.

namespace {
constexpr int CC = 128;
constexpr int EE = 10;
constexpr int NZ = 68;
// z row offsets inside zbuf
constexpr int Z31 = 0;   // 33 rows: z3 for 1o
constexpr int Z21 = 33;  // 6 rows
constexpr int Z11 = 39;  // 1 row
constexpr int Z30 = 40;  // 23 rows
constexpr int Z20 = 63;  // 4 rows
constexpr int Z10 = 67;  // 1 row
}

__global__ __launch_bounds__(1024) void symcon_kernel(
    const float* __restrict__ x,      // [B][C][16]
    const float* __restrict__ y,      // [B][E]
    const float* __restrict__ U1_0e,  // [16][1]
    const float* __restrict__ U2_0e,  // [16][16][4]
    const float* __restrict__ U3_0e,  // [16][16][16][23]
    const float* __restrict__ U1_1o,  // [3][16][1]
    const float* __restrict__ U2_1o,  // [3][16][16][6]
    const float* __restrict__ U3_1o,  // [3][16][16][16][33]
    const float* __restrict__ w1_0e,  // [E][1][C]
    const float* __restrict__ w2_0e,  // [E][4][C]
    const float* __restrict__ w3_0e,  // [E][23][C]
    const float* __restrict__ w1_1o,  // [E][1][C]
    const float* __restrict__ w2_1o,  // [E][6][C]
    const float* __restrict__ w3_1o,  // [E][33][C]
    float* __restrict__ out)          // [B][512]
{
  __shared__ float x_lds[16][64];
  __shared__ float zbuf[NZ][64];
  __shared__ float red[16][64];

  const int tid   = threadIdx.x;
  const int pair0 = blockIdx.x * 64;

  // ---- stage x: x_lds[i][n] = x[(pair0+n)*16 + i] ----
  {
    const int n = tid & 63;
    const int i = tid >> 6;   // 0..15 (block has exactly 16*64 threads)
    x_lds[i][n] = x[(size_t)(pair0 + n) * 16 + i];
  }
  // ---- stage z: zbuf[zi][n] = sum_e w*[e][k][c] * y[b][e] ----
  for (int t = tid; t < NZ * 64; t += 1024) {
    const int n  = t & 63;
    const int zi = t >> 6;   // 0..67
    const int p  = pair0 + n;
    const int b  = p >> 7;
    const int c  = p & 127;
    const float* yb = y + b * EE;
    const float* wsrc;
    int stride;
    if      (zi < Z21) { wsrc = w3_1o + (zi      ) * CC + c; stride = 33 * CC; }
    else if (zi < Z11) { wsrc = w2_1o + (zi - Z21) * CC + c; stride =  6 * CC; }
    else if (zi < Z30) { wsrc = w1_1o +                   c; stride =  1 * CC; }
    else if (zi < Z20) { wsrc = w3_0e + (zi - Z30) * CC + c; stride = 23 * CC; }
    else if (zi < Z10) { wsrc = w2_0e + (zi - Z20) * CC + c; stride =  4 * CC; }
    else               { wsrc = w1_0e +                   c; stride =  1 * CC; }
    float a = 0.f;
    #pragma unroll
    for (int e = 0; e < EE; ++e) a += wsrc[e * stride] * yb[e];
    zbuf[zi][n] = a;
  }
  __syncthreads();

  const int wv   = tid >> 6;      // wave 0..15
  const int lane = tid & 63;
  const int lr   = lane >> 3;     // row-group 0..7
  const int n0   = (lane & 7) * 8;// this lane's 8 pairs: n0..n0+7

  float acc[8][8];
  #pragma unroll
  for (int r = 0; r < 8; ++r)
    #pragma unroll
    for (int j = 0; j < 8; ++j) acc[r][j] = 0.f;

  if (wv < 12) {
    // ---- 1o GEMM: rows m0..m0+7, K = 16*33 U3 cols + 6 U2 cols ----
    const int m0 = wv * 64 + lr * 8;
    const float* U3row = U3_1o + (size_t)m0 * 528;
    for (int i = 0; i < 16; ++i) {
      float xr[8];
      #pragma unroll
      for (int j = 0; j < 8; ++j) xr[j] = x_lds[i][n0 + j];
      const float* Ui = U3row + i * 33;
      for (int k = 0; k < 33; ++k) {
        float pj[8];
        #pragma unroll
        for (int j = 0; j < 8; ++j) pj[j] = xr[j] * zbuf[Z31 + k][n0 + j];
        #pragma unroll
        for (int r = 0; r < 8; ++r) {
          const float u = Ui[r * 528 + k];
          #pragma unroll
          for (int j = 0; j < 8; ++j) acc[r][j] += u * pj[j];
        }
      }
    }
    const float* U2row = U2_1o + m0 * 6;
    #pragma unroll
    for (int k = 0; k < 6; ++k) {
      float pj[8];
      #pragma unroll
      for (int j = 0; j < 8; ++j) pj[j] = zbuf[Z21 + k][n0 + j];
      #pragma unroll
      for (int r = 0; r < 8; ++r) {
        const float u = U2row[r * 6 + k];
        #pragma unroll
        for (int j = 0; j < 8; ++j) acc[r][j] += u * pj[j];
      }
    }
  } else {
    // ---- 0e GEMM: rows (wv-12)*64+lr*8 .., K = 16*23 + 4 ----
    const int m0 = (wv - 12) * 64 + lr * 8;
    const float* U3row = U3_0e + (size_t)m0 * 368;
    for (int i = 0; i < 16; ++i) {
      float xr[8];
      #pragma unroll
      for (int j = 0; j < 8; ++j) xr[j] = x_lds[i][n0 + j];
      const float* Ui = U3row + i * 23;
      for (int k = 0; k < 23; ++k) {
        float pj[8];
        #pragma unroll
        for (int j = 0; j < 8; ++j) pj[j] = xr[j] * zbuf[Z30 + k][n0 + j];
        #pragma unroll
        for (int r = 0; r < 8; ++r) {
          const float u = Ui[r * 368 + k];
          #pragma unroll
          for (int j = 0; j < 8; ++j) acc[r][j] += u * pj[j];
        }
      }
    }
    const float* U2row = U2_0e + m0 * 4;
    #pragma unroll
    for (int k = 0; k < 4; ++k) {
      float pj[8];
      #pragma unroll
      for (int j = 0; j < 8; ++j) pj[j] = zbuf[Z20 + k][n0 + j];
      #pragma unroll
      for (int r = 0; r < 8; ++r) {
        const float u = U2row[r * 4 + k];
        #pragma unroll
        for (int j = 0; j < 8; ++j) acc[r][j] += u * pj[j];
      }
    }
  }

  // ---- epilogue: fold Q[q]=x[qa]*x[qb], reduce over rows ----
  float s[8];
  #pragma unroll
  for (int j = 0; j < 8; ++j) s[j] = 0.f;
  {
    const int qbase = (wv < 12 ? (wv & 3) : (wv - 12)) * 64 + lr * 8;
    #pragma unroll
    for (int r = 0; r < 8; ++r) {
      const int qa = (qbase + r) >> 4;
      const int qb = (qbase + r) & 15;
      #pragma unroll
      for (int j = 0; j < 8; ++j)
        s[j] += acc[r][j] * (x_lds[qa][n0 + j] * x_lds[qb][n0 + j]);
    }
  }
  // butterfly over lane bits 3..5 (the lr dimension)
  #pragma unroll
  for (int off = 8; off < 64; off <<= 1)
    #pragma unroll
    for (int j = 0; j < 8; ++j) s[j] += __shfl_xor(s[j], off);
  if (lr == 0) {
    #pragma unroll
    for (int j = 0; j < 8; ++j) red[wv][n0 + j] = s[j];
  }
  __syncthreads();

  // ---- final combine + U1 terms + store ----
  if (tid < 256) {
    const int n    = tid & 63;
    const int slot = tid >> 6;  // 0..2 = 1o w, 3 = 0e
    const int p = pair0 + n;
    const int b = p >> 7;
    const int c = p & 127;
    if (slot < 3) {
      const int w = slot;
      float v = red[4 * w][n] + red[4 * w + 1][n] + red[4 * w + 2][n] + red[4 * w + 3][n];
      float u1 = 0.f;
      #pragma unroll
      for (int xx = 0; xx < 16; ++xx) u1 += U1_1o[w * 16 + xx] * x_lds[xx][n];
      v += zbuf[Z11][n] * u1;
      out[(size_t)b * 512 + 128 + c * 3 + w] = v;
    } else {
      float v = red[12][n] + red[13][n] + red[14][n] + red[15][n];
      float u1 = 0.f;
      #pragma unroll
      for (int ww = 0; ww < 16; ++ww) u1 += U1_0e[ww] * x_lds[ww][n];
      v += zbuf[Z10][n] * u1;
      out[(size_t)b * 512 + c] = v;
    }
  }
}

extern "C" void kernel_launch(void* const* d_in, const int* in_sizes, int n_in,
                              void* d_out, int out_size, void* d_ws, size_t ws_size,
                              hipStream_t stream) {
  const float* x     = (const float*)d_in[0];
  const float* y     = (const float*)d_in[1];
  const float* U1_0e = (const float*)d_in[2];
  const float* U2_0e = (const float*)d_in[3];
  const float* U3_0e = (const float*)d_in[4];
  const float* U1_1o = (const float*)d_in[5];
  const float* U2_1o = (const float*)d_in[6];
  const float* U3_1o = (const float*)d_in[7];
  const float* w1_0e = (const float*)d_in[8];
  const float* w2_0e = (const float*)d_in[9];
  const float* w3_0e = (const float*)d_in[10];
  const float* w1_1o = (const float*)d_in[11];
  const float* w2_1o = (const float*)d_in[12];
  const float* w3_1o = (const float*)d_in[13];
  (void)in_sizes; (void)n_in; (void)out_size; (void)d_ws; (void)ws_size;

  hipLaunchKernelGGL(symcon_kernel, dim3(256), dim3(1024), 0, stream,
                     x, y, U1_0e, U2_0e, U3_0e, U1_1o, U2_1o, U3_1o,
                     w1_0e, w2_0e, w3_0e, w1_1o, w2_1o, w3_1o,
                     (float*)d_out);
}

// Round 2
// 983.691 us; speedup vs baseline: 1.6432x; 1.6432x over previous
//
#include <hip/hip_runtime.h>

// SymmetricContraction (MACE-style), B=128, C=128, E=10, L=16.
// Algebraic collapse: out is a full contraction of U-tensors with rank-1
// products of per-(b,c) vectors; no big intermediates needed.
//   pairs p = b*128+c (16384). 1o rows m=(w,q): w=0..2, q=(x<<4)|v (256 rows/w).
//   0e rows q=(w<<4)|x (256 rows).
//   acc[row][p] = sum_{i,k} U3[row][i][k] * x[p][i]*z3[p][k]  (+ U2 cols w/ z2)
//   out += sum_rows Q[p][q] * acc[row][p],  Q[p][q]=x[p][q>>4]*x[p][q&15]
//   plus tiny U1 terms in the epilogue.
// Round-2 fix: round-1 used 1024-thread blocks -> 64-VGPR cap -> acc[8][8]
// spilled (4.1 GB scratch WRITE_SIZE). Now 256 threads, launch_bounds(256,2),
// each wave owns one output group, 32 pairs/block, 512 blocks.

namespace {
constexpr int CC = 128;
constexpr int EE = 10;
constexpr int NZ = 68;
constexpr int NP = 32;   // pairs per block
// z row offsets inside zbuf
constexpr int Z31 = 0;   // 33 rows: z3 for 1o
constexpr int Z21 = 33;  // 6 rows
constexpr int Z11 = 39;  // 1 row
constexpr int Z30 = 40;  // 23 rows
constexpr int Z20 = 63;  // 4 rows
constexpr int Z10 = 67;  // 1 row
}

__global__ __launch_bounds__(256, 2) void symcon_kernel(
    const float* __restrict__ x,      // [B][C][16]
    const float* __restrict__ y,      // [B][E]
    const float* __restrict__ U1_0e,  // [16][1]
    const float* __restrict__ U2_0e,  // [16][16][4]
    const float* __restrict__ U3_0e,  // [16][16][16][23]
    const float* __restrict__ U1_1o,  // [3][16][1]
    const float* __restrict__ U2_1o,  // [3][16][16][6]
    const float* __restrict__ U3_1o,  // [3][16][16][16][33]
    const float* __restrict__ w1_0e,  // [E][1][C]
    const float* __restrict__ w2_0e,  // [E][4][C]
    const float* __restrict__ w3_0e,  // [E][23][C]
    const float* __restrict__ w1_1o,  // [E][1][C]
    const float* __restrict__ w2_1o,  // [E][6][C]
    const float* __restrict__ w3_1o,  // [E][33][C]
    float* __restrict__ out)          // [B][512]
{
  __shared__ float x_lds[16][NP];
  __shared__ float zbuf[NZ][NP];

  const int tid   = threadIdx.x;
  const int pair0 = blockIdx.x * NP;

  // ---- stage x: x_lds[i][n] = x[(pair0+n)*16 + i] ----
  for (int t = tid; t < 16 * NP; t += 256) {
    const int i = t >> 5;
    const int n = t & 31;
    x_lds[i][n] = x[(size_t)(pair0 + n) * 16 + i];
  }
  // ---- stage z: zbuf[zi][n] = sum_e w*[e][k][c] * y[b][e] ----
  for (int t = tid; t < NZ * NP; t += 256) {
    const int n  = t & 31;
    const int zi = t >> 5;   // 0..67
    const int p  = pair0 + n;
    const int b  = p >> 7;
    const int c  = p & 127;
    const float* yb = y + b * EE;
    const float* wsrc;
    int stride;
    if      (zi < Z21) { wsrc = w3_1o + (zi      ) * CC + c; stride = 33 * CC; }
    else if (zi < Z11) { wsrc = w2_1o + (zi - Z21) * CC + c; stride =  6 * CC; }
    else if (zi < Z30) { wsrc = w1_1o +                   c; stride =  1 * CC; }
    else if (zi < Z20) { wsrc = w3_0e + (zi - Z30) * CC + c; stride = 23 * CC; }
    else if (zi < Z10) { wsrc = w2_0e + (zi - Z20) * CC + c; stride =  4 * CC; }
    else               { wsrc = w1_0e +                   c; stride =  1 * CC; }
    float a = 0.f;
    #pragma unroll
    for (int e = 0; e < EE; ++e) a += wsrc[e * stride] * yb[e];
    zbuf[zi][n] = a;
  }
  __syncthreads();

  const int wv   = tid >> 6;      // wave 0..3: 0..2 = 1o w, 3 = 0e
  const int lane = tid & 63;
  const int lr   = lane >> 2;     // row-group 0..15
  const int n0   = (lane & 3) * 8;// this lane's 8 pairs

  float s[8];
  #pragma unroll
  for (int j = 0; j < 8; ++j) s[j] = 0.f;

  for (int ch = 0; ch < 2; ++ch) {
    const int q0 = ch * 128 + lr * 8;   // 8 rows q0..q0+7 of this wave's group
    float acc[8][8];
    #pragma unroll
    for (int r = 0; r < 8; ++r)
      #pragma unroll
      for (int j = 0; j < 8; ++j) acc[r][j] = 0.f;

    if (wv < 3) {
      // ---- 1o: rows (wv, q0..q0+7), K = 16*33 U3 cols + 6 U2 cols ----
      const float* U3row = U3_1o + (size_t)(wv * 256 + q0) * 528;
      for (int i = 0; i < 16; ++i) {
        float xr[8];
        #pragma unroll
        for (int j = 0; j < 8; ++j) xr[j] = x_lds[i][n0 + j];
        const float* Ui = U3row + i * 33;
        for (int k = 0; k < 33; ++k) {
          float pj[8];
          #pragma unroll
          for (int j = 0; j < 8; ++j) pj[j] = xr[j] * zbuf[Z31 + k][n0 + j];
          #pragma unroll
          for (int r = 0; r < 8; ++r) {
            const float u = Ui[r * 528 + k];
            #pragma unroll
            for (int j = 0; j < 8; ++j) acc[r][j] += u * pj[j];
          }
        }
      }
      const float* U2row = U2_1o + (wv * 256 + q0) * 6;
      #pragma unroll
      for (int k = 0; k < 6; ++k) {
        float pj[8];
        #pragma unroll
        for (int j = 0; j < 8; ++j) pj[j] = zbuf[Z21 + k][n0 + j];
        #pragma unroll
        for (int r = 0; r < 8; ++r) {
          const float u = U2row[r * 6 + k];
          #pragma unroll
          for (int j = 0; j < 8; ++j) acc[r][j] += u * pj[j];
        }
      }
    } else {
      // ---- 0e: rows q0..q0+7, K = 16*23 + 4 ----
      const float* U3row = U3_0e + (size_t)q0 * 368;
      for (int i = 0; i < 16; ++i) {
        float xr[8];
        #pragma unroll
        for (int j = 0; j < 8; ++j) xr[j] = x_lds[i][n0 + j];
        const float* Ui = U3row + i * 23;
        for (int k = 0; k < 23; ++k) {
          float pj[8];
          #pragma unroll
          for (int j = 0; j < 8; ++j) pj[j] = xr[j] * zbuf[Z30 + k][n0 + j];
          #pragma unroll
          for (int r = 0; r < 8; ++r) {
            const float u = Ui[r * 368 + k];
            #pragma unroll
            for (int j = 0; j < 8; ++j) acc[r][j] += u * pj[j];
          }
        }
      }
      const float* U2row = U2_0e + q0 * 4;
      #pragma unroll
      for (int k = 0; k < 4; ++k) {
        float pj[8];
        #pragma unroll
        for (int j = 0; j < 8; ++j) pj[j] = zbuf[Z20 + k][n0 + j];
        #pragma unroll
        for (int r = 0; r < 8; ++r) {
          const float u = U2row[r * 4 + k];
          #pragma unroll
          for (int j = 0; j < 8; ++j) acc[r][j] += u * pj[j];
        }
      }
    }

    // ---- fold Q[q]=x[qa]*x[qb] into persistent s ----
    #pragma unroll
    for (int r = 0; r < 8; ++r) {
      const int q  = q0 + r;
      const int qa = q >> 4;
      const int qb = q & 15;
      #pragma unroll
      for (int j = 0; j < 8; ++j)
        s[j] += acc[r][j] * (x_lds[qa][n0 + j] * x_lds[qb][n0 + j]);
    }
  }

  // ---- reduce over the 16 row-groups (lane bits 2..5) ----
  #pragma unroll
  for (int off = 4; off < 64; off <<= 1)
    #pragma unroll
    for (int j = 0; j < 8; ++j) s[j] += __shfl_xor(s[j], off);

  // ---- lanes 0..3 write: + U1 terms ----
  if (lane < 4) {
    #pragma unroll
    for (int j = 0; j < 8; ++j) {
      const int n = n0 + j;
      const int p = pair0 + n;
      const int b = p >> 7;
      const int c = p & 127;
      if (wv < 3) {
        float u1 = 0.f;
        #pragma unroll
        for (int xx = 0; xx < 16; ++xx) u1 += U1_1o[wv * 16 + xx] * x_lds[xx][n];
        out[(size_t)b * 512 + 128 + c * 3 + wv] = s[j] + zbuf[Z11][n] * u1;
      } else {
        float u1 = 0.f;
        #pragma unroll
        for (int xx = 0; xx < 16; ++xx) u1 += U1_0e[xx] * x_lds[xx][n];
        out[(size_t)b * 512 + c] = s[j] + zbuf[Z10][n] * u1;
      }
    }
  }
}

extern "C" void kernel_launch(void* const* d_in, const int* in_sizes, int n_in,
                              void* d_out, int out_size, void* d_ws, size_t ws_size,
                              hipStream_t stream) {
  const float* x     = (const float*)d_in[0];
  const float* y     = (const float*)d_in[1];
  const float* U1_0e = (const float*)d_in[2];
  const float* U2_0e = (const float*)d_in[3];
  const float* U3_0e = (const float*)d_in[4];
  const float* U1_1o = (const float*)d_in[5];
  const float* U2_1o = (const float*)d_in[6];
  const float* U3_1o = (const float*)d_in[7];
  const float* w1_0e = (const float*)d_in[8];
  const float* w2_0e = (const float*)d_in[9];
  const float* w3_0e = (const float*)d_in[10];
  const float* w1_1o = (const float*)d_in[11];
  const float* w2_1o = (const float*)d_in[12];
  const float* w3_1o = (const float*)d_in[13];
  (void)in_sizes; (void)n_in; (void)out_size; (void)d_ws; (void)ws_size;

  hipLaunchKernelGGL(symcon_kernel, dim3(512), dim3(256), 0, stream,
                     x, y, U1_0e, U2_0e, U3_0e, U1_1o, U2_1o, U3_1o,
                     w1_0e, w2_0e, w3_0e, w1_1o, w2_1o, w3_1o,
                     (float*)d_out);
}

// Round 3
// 557.699 us; speedup vs baseline: 2.8983x; 1.7638x over previous
//
#include <hip/hip_runtime.h>

// SymmetricContraction (MACE-style), B=128, C=128, E=10, L=16.
// out0[b,c] = sum_{q=(w<<4)|x} Q[q] * ( sum_{i,k} U3_0e[q][i][k]*x_i*z3_k
//                                       + sum_k U2_0e[q][k]*z2_k )  + z1*sum U1*x
// out1[b,c,w] analogous with q=(x<<4)|v over U3_1o[w].
// Q[q] = x[q>>4]*x[q&15];  z*_k = sum_e w*[e][k][c]*y[b][e].
//
// Round-3 structure: lane == pair (64 pairs/block). All U indexing is
// wave-uniform -> scalar s_load, FMA reads SGPR operand. x/z per-lane in
// registers; inner loop has NO vector-memory ops. 8 waves/block: waves
// {2g,2g+1} split the 256 rows of group g (g=0..2: 1o w=g, g=3: 0e).

namespace {
constexpr int EE = 10;
}

__global__ __launch_bounds__(512, 2) void symcon_kernel(
    const float* __restrict__ x,      // [B][C][16]
    const float* __restrict__ y,      // [B][E]
    const float* __restrict__ U1_0e,  // [16][1]
    const float* __restrict__ U2_0e,  // [16][16][4]
    const float* __restrict__ U3_0e,  // [16][16][16][23]
    const float* __restrict__ U1_1o,  // [3][16][1]
    const float* __restrict__ U2_1o,  // [3][16][16][6]
    const float* __restrict__ U3_1o,  // [3][16][16][16][33]
    const float* __restrict__ w1_0e,  // [E][1][C]
    const float* __restrict__ w2_0e,  // [E][4][C]
    const float* __restrict__ w3_0e,  // [E][23][C]
    const float* __restrict__ w1_1o,  // [E][1][C]
    const float* __restrict__ w2_1o,  // [E][6][C]
    const float* __restrict__ w3_1o,  // [E][33][C]
    float* __restrict__ out)          // [B][512]
{
  __shared__ float x_lds[16][64];
  __shared__ float red[8][64];

  const int tid  = threadIdx.x;
  const int lane = tid & 63;
  const int wv   = __builtin_amdgcn_readfirstlane(tid >> 6);  // 0..7, uniform
  const int blk  = blockIdx.x;           // 0..255
  const int pair0 = blk * 64;
  const int b    = blk >> 1;             // batch, uniform per block
  const int c    = ((blk & 1) << 6) + lane;

  // ---- stage x: x_lds[i][n] = x[(pair0+n)*16 + i] ----
  for (int t = tid; t < 16 * 64; t += 512) {
    const int i = t >> 6;
    const int n = t & 63;
    x_lds[i][n] = x[(size_t)(pair0 + n) * 16 + i];
  }
  __syncthreads();

  // ---- per-lane y (b uniform -> scalar loads) ----
  float yv[EE];
  #pragma unroll
  for (int e = 0; e < EE; ++e) yv[e] = y[b * EE + e];

  const int grp  = wv >> 1;   // 0..2 = 1o w, 3 = 0e (uniform)
  const int half = wv & 1;    // row half (uniform)
  const int q00  = half * 128;
  float s = 0.f;

  if (grp < 3) {
    // ---- z vectors in registers ----
    float z3[33];
    #pragma unroll
    for (int k = 0; k < 33; ++k) {
      float a = 0.f;
      #pragma unroll
      for (int e = 0; e < EE; ++e) a += w3_1o[(e * 33 + k) * 128 + c] * yv[e];
      z3[k] = a;
    }
    float z2[6];
    #pragma unroll
    for (int k = 0; k < 6; ++k) {
      float a = 0.f;
      #pragma unroll
      for (int e = 0; e < EE; ++e) a += w2_1o[(e * 6 + k) * 128 + c] * yv[e];
      z2[k] = a;
    }

    const float* __restrict__ U3base = U3_1o + ((size_t)grp * 256 + q00) * 528;
    const float* __restrict__ U2base = U2_1o + (grp * 256 + q00) * 6;

    #pragma unroll 1
    for (int rb = 0; rb < 16; ++rb) {
      float acc[8];
      #pragma unroll
      for (int r = 0; r < 8; ++r) acc[r] = 0.f;

      #pragma unroll 2
      for (int i = 0; i < 16; ++i) {
        const float xi = x_lds[i][lane];
        float pj[33];
        #pragma unroll
        for (int k = 0; k < 33; ++k) pj[k] = xi * z3[k];
        const float* __restrict__ Ur = U3base + (size_t)(rb * 8) * 528 + i * 33;
        #pragma unroll
        for (int r = 0; r < 8; ++r) {
          #pragma unroll
          for (int k = 0; k < 33; ++k) acc[r] += Ur[r * 528 + k] * pj[k];
        }
      }
      // U2 terms + Q-fold
      #pragma unroll
      for (int r = 0; r < 8; ++r) {
        const int q = q00 + rb * 8 + r;
        float a2 = acc[r];
        #pragma unroll
        for (int k = 0; k < 6; ++k) a2 += U2base[(rb * 8 + r) * 6 + k] * z2[k];
        s += a2 * (x_lds[q >> 4][lane] * x_lds[q & 15][lane]);
      }
    }
  } else {
    float z3[23];
    #pragma unroll
    for (int k = 0; k < 23; ++k) {
      float a = 0.f;
      #pragma unroll
      for (int e = 0; e < EE; ++e) a += w3_0e[(e * 23 + k) * 128 + c] * yv[e];
      z3[k] = a;
    }
    float z2[4];
    #pragma unroll
    for (int k = 0; k < 4; ++k) {
      float a = 0.f;
      #pragma unroll
      for (int e = 0; e < EE; ++e) a += w2_0e[(e * 4 + k) * 128 + c] * yv[e];
      z2[k] = a;
    }

    const float* __restrict__ U3base = U3_0e + (size_t)q00 * 368;
    const float* __restrict__ U2base = U2_0e + q00 * 4;

    #pragma unroll 1
    for (int rb = 0; rb < 16; ++rb) {
      float acc[8];
      #pragma unroll
      for (int r = 0; r < 8; ++r) acc[r] = 0.f;

      #pragma unroll 2
      for (int i = 0; i < 16; ++i) {
        const float xi = x_lds[i][lane];
        float pj[23];
        #pragma unroll
        for (int k = 0; k < 23; ++k) pj[k] = xi * z3[k];
        const float* __restrict__ Ur = U3base + (size_t)(rb * 8) * 368 + i * 23;
        #pragma unroll
        for (int r = 0; r < 8; ++r) {
          #pragma unroll
          for (int k = 0; k < 23; ++k) acc[r] += Ur[r * 368 + k] * pj[k];
        }
      }
      #pragma unroll
      for (int r = 0; r < 8; ++r) {
        const int q = q00 + rb * 8 + r;
        float a2 = acc[r];
        #pragma unroll
        for (int k = 0; k < 4; ++k) a2 += U2base[(rb * 8 + r) * 4 + k] * z2[k];
        s += a2 * (x_lds[q >> 4][lane] * x_lds[q & 15][lane]);
      }
    }
  }

  red[wv][lane] = s;
  __syncthreads();

  // ---- combine halves + U1 terms + store (threads 0..255) ----
  if (tid < 256) {
    const int slot = tid >> 6;   // 0..2 = 1o w, 3 = 0e
    const int n    = tid & 63;
    const int cc   = ((blk & 1) << 6) + n;
    float u1 = 0.f, z1 = 0.f, v;
    if (slot < 3) {
      #pragma unroll
      for (int xx = 0; xx < 16; ++xx) u1 += U1_1o[slot * 16 + xx] * x_lds[xx][n];
      #pragma unroll
      for (int e = 0; e < EE; ++e) z1 += w1_1o[e * 128 + cc] * y[b * EE + e];
      v = red[2 * slot][n] + red[2 * slot + 1][n] + z1 * u1;
      out[(size_t)b * 512 + 128 + cc * 3 + slot] = v;
    } else {
      #pragma unroll
      for (int xx = 0; xx < 16; ++xx) u1 += U1_0e[xx] * x_lds[xx][n];
      #pragma unroll
      for (int e = 0; e < EE; ++e) z1 += w1_0e[e * 128 + cc] * y[b * EE + e];
      v = red[6][n] + red[7][n] + z1 * u1;
      out[(size_t)b * 512 + cc] = v;
    }
  }
}

extern "C" void kernel_launch(void* const* d_in, const int* in_sizes, int n_in,
                              void* d_out, int out_size, void* d_ws, size_t ws_size,
                              hipStream_t stream) {
  const float* x     = (const float*)d_in[0];
  const float* y     = (const float*)d_in[1];
  const float* U1_0e = (const float*)d_in[2];
  const float* U2_0e = (const float*)d_in[3];
  const float* U3_0e = (const float*)d_in[4];
  const float* U1_1o = (const float*)d_in[5];
  const float* U2_1o = (const float*)d_in[6];
  const float* U3_1o = (const float*)d_in[7];
  const float* w1_0e = (const float*)d_in[8];
  const float* w2_0e = (const float*)d_in[9];
  const float* w3_0e = (const float*)d_in[10];
  const float* w1_1o = (const float*)d_in[11];
  const float* w2_1o = (const float*)d_in[12];
  const float* w3_1o = (const float*)d_in[13];
  (void)in_sizes; (void)n_in; (void)out_size; (void)d_ws; (void)ws_size;

  hipLaunchKernelGGL(symcon_kernel, dim3(256), dim3(512), 0, stream,
                     x, y, U1_0e, U2_0e, U3_0e, U1_1o, U2_1o, U3_1o,
                     w1_0e, w2_0e, w3_0e, w1_1o, w2_1o, w3_1o,
                     (float*)d_out);
}

// Round 4
// 46.004 us; speedup vs baseline: 35.1352x; 12.1227x over previous
//
#include <hip/hip_runtime.h>

// SymmetricContraction (MACE-style), B=128, C=128, E=10, L=16.
// Collapsed to GEMM + Q-fold:
//   D[m,p] = sum_kappa A[m,kappa] * Bm[kappa,p]
//     A1 = U3_1o as [768][528] ++ U2_1o cols -> [768][544] bf16 (ws)
//     A0 = U3_0e as [256][368] ++ U2_0e cols -> [256][384] bf16 (ws)
//     Bm[kappa=(i,k), p] = x[i,p] * z3[k,p]; U2 rows = z2[k,p]; pad = 0
//   out[group,p] = sum_m Q[m,p]*D[m,p] + z1*U1-term,  Q = x[qa,p]*x[qb,p]
// z*[k,p] = sum_e w*[e][k][c]*y[b][e]  (p = b*128+c)
//
// Round 4: MFMA (16x16x32 bf16). 256 blocks x 512 thr; block = 64 pairs;
// wave wv<6 -> 1o rows wv*128.., wv 6,7 -> 0e rows (wv-6)*128..
// A frags from global bf16 ws (16B/lane, full-line gather), B built in LDS
// (double-buffered [64][40] bf16, 16B-aligned rows). Fallback (ws too
// small): round-3 scalar kernel, known good.

typedef float  f32x4  __attribute__((ext_vector_type(4)));
typedef short  short8 __attribute__((ext_vector_type(8)));

namespace {
constexpr int EE = 10;
constexpr int LDA1 = 544;                 // 528 U3 + 6 U2 + 10 zero
constexpr int LDA0 = 384;                 // 368 U3 + 4 U2 + 12 zero
constexpr int A1_ELEMS = 768 * LDA1;      // 417792
constexpr int A0_ELEMS = 256 * LDA0;      // 98304
constexpr size_t WS_NEED = (size_t)(A1_ELEMS + A0_ELEMS) * 2;
// zbuf row offsets
constexpr int Z31 = 0;   // 33
constexpr int Z21 = 33;  // 6
constexpr int Z11 = 39;  // 1
constexpr int Z30 = 40;  // 23
constexpr int Z20 = 63;  // 4
constexpr int Z10 = 67;  // 1
constexpr int NZ  = 68;

__device__ __forceinline__ unsigned short f2bf(float f) {
  union { float f; unsigned u; } v; v.f = f;
  unsigned r = v.u + 0x7FFFu + ((v.u >> 16) & 1u);
  return (unsigned short)(r >> 16);
}
}

// ---- prep: build padded bf16 A into ws ----
__global__ __launch_bounds__(256) void prep_kernel(
    const float* __restrict__ U3_1o, const float* __restrict__ U2_1o,
    const float* __restrict__ U3_0e, const float* __restrict__ U2_0e,
    unsigned short* __restrict__ wsA)
{
  int idx = blockIdx.x * 256 + threadIdx.x;
  if (idx < A1_ELEMS) {
    int m = idx / LDA1, k = idx - m * LDA1;
    float v = (k < 528) ? U3_1o[m * 528 + k]
            : (k < 534) ? U2_1o[m * 6 + (k - 528)] : 0.f;
    wsA[idx] = f2bf(v);
  } else if (idx < A1_ELEMS + A0_ELEMS) {
    int j = idx - A1_ELEMS;
    int m = j / LDA0, k = j - m * LDA0;
    float v = (k < 368) ? U3_0e[m * 368 + k]
            : (k < 372) ? U2_0e[m * 4 + (k - 368)] : 0.f;
    wsA[idx] = f2bf(v);
  }
}

// ---- main MFMA kernel ----
__global__ __launch_bounds__(512, 2) void symcon_mfma(
    const float* __restrict__ x,      // [B][C][16]
    const float* __restrict__ y,      // [B][E]
    const float* __restrict__ U1_0e, const float* __restrict__ U1_1o,
    const float* __restrict__ w1_0e, const float* __restrict__ w2_0e,
    const float* __restrict__ w3_0e, const float* __restrict__ w1_1o,
    const float* __restrict__ w2_1o, const float* __restrict__ w3_1o,
    const unsigned short* __restrict__ wsA,
    float* __restrict__ out)          // [B][512]
{
  __shared__ float x_lds[16][64];
  __shared__ float zbuf[NZ][64];
  __shared__ unsigned short B1buf[2][64][40];
  __shared__ unsigned short B0buf[2][64][40];
  __shared__ float red[8][64];

  const int tid   = threadIdx.x;
  const int blk   = blockIdx.x;       // 0..255
  const int pair0 = blk * 64;
  const int b     = blk >> 1;         // uniform

  // ---- stage x ----
  for (int t = tid; t < 16 * 64; t += 512) {
    const int i = t >> 6, n = t & 63;
    x_lds[i][n] = x[(size_t)(pair0 + n) * 16 + i];
  }
  // ---- stage z ----
  for (int t = tid; t < NZ * 64; t += 512) {
    const int n  = t & 63;
    const int zi = t >> 6;
    const int c  = ((blk & 1) << 6) + n;
    const float* yb = y + b * EE;
    const float* wsrc; int stride;
    if      (zi < Z21) { wsrc = w3_1o + (zi      ) * 128 + c; stride = 33 * 128; }
    else if (zi < Z11) { wsrc = w2_1o + (zi - Z21) * 128 + c; stride =  6 * 128; }
    else if (zi < Z30) { wsrc = w1_1o +                    c; stride =  1 * 128; }
    else if (zi < Z20) { wsrc = w3_0e + (zi - Z30) * 128 + c; stride = 23 * 128; }
    else if (zi < Z10) { wsrc = w2_0e + (zi - Z20) * 128 + c; stride =  4 * 128; }
    else               { wsrc = w1_0e +                    c; stride =  1 * 128; }
    float a = 0.f;
    #pragma unroll
    for (int e = 0; e < EE; ++e) a += wsrc[e * stride] * yb[e];
    zbuf[zi][n] = a;
  }
  __syncthreads();

  // ---- B-tile builders (all 512 threads) ----
  auto b1val = [&](int kap, int p) -> unsigned short {
    float v;
    if (kap < 528) { int i = kap / 33, kk = kap - i * 33; v = x_lds[i][p] * zbuf[Z31 + kk][p]; }
    else if (kap < 534) v = zbuf[Z21 + (kap - 528)][p];
    else v = 0.f;
    return f2bf(v);
  };
  auto b0val = [&](int kap, int p) -> unsigned short {
    float v;
    if (kap < 368) { int i = kap / 23, kk = kap - i * 23; v = x_lds[i][p] * zbuf[Z30 + kk][p]; }
    else if (kap < 372) v = zbuf[Z20 + (kap - 368)][p];
    else v = 0.f;
    return f2bf(v);
  };
  auto buildB = [&](int tt) {
    const int bb = tt & 1;
    #pragma unroll
    for (int pass = 0; pass < 2; ++pass) {
      const int idx = tid + pass * 512;     // 0..1023
      const int p = idx & 63, kr2 = idx >> 6;
      const int k0 = tt * 32 + kr2 * 2;
      unsigned lo = b1val(k0, p), hi = b1val(k0 + 1, p);
      *(unsigned*)&B1buf[bb][p][kr2 * 2] = lo | (hi << 16);
    }
    if (tt < 12) {
      #pragma unroll
      for (int pass = 0; pass < 2; ++pass) {
        const int idx = tid + pass * 512;
        const int p = idx & 63, kr2 = idx >> 6;
        const int k0 = tt * 32 + kr2 * 2;
        unsigned lo = b0val(k0, p), hi = b0val(k0 + 1, p);
        *(unsigned*)&B0buf[bb][p][kr2 * 2] = lo | (hi << 16);
      }
    }
  };

  buildB(0);

  const int lane  = tid & 63;
  const int wv    = tid >> 6;          // 0..7 (uniform per wave)
  const bool is1o = (wv < 6);
  const int q00   = (wv & 1) * 128;
  const int mbase = (is1o ? wv : (wv - 6)) * 128;
  const unsigned short* Abase = is1o ? wsA : (wsA + A1_ELEMS);
  const int lda    = is1o ? LDA1 : LDA0;
  const int mySteps = is1o ? 17 : 12;

  // per-mf A row pointers (lane: row = l&15, kgroup = l>>4)
  const unsigned short* aPtr[8];
  #pragma unroll
  for (int mf = 0; mf < 8; ++mf)
    aPtr[mf] = Abase + (size_t)(mbase + mf * 16 + (lane & 15)) * lda + (lane >> 4) * 8;

  f32x4 acc[8][4] = {};

  __syncthreads();   // B(0) ready

  #pragma unroll 1
  for (int t = 0; t < 17; ++t) {
    if (t < mySteps) {
      short8 af[8];
      #pragma unroll
      for (int mf = 0; mf < 8; ++mf)
        af[mf] = *(const short8*)(aPtr[mf] + t * 32);
      short8 bfr[4];
      const unsigned short (*Bb)[40] = is1o ? B1buf[t & 1] : B0buf[t & 1];
      #pragma unroll
      for (int nf = 0; nf < 4; ++nf)
        bfr[nf] = *(const short8*)&Bb[nf * 16 + (lane & 15)][(lane >> 4) * 8];
      if (t + 1 < 17) buildB(t + 1);
      #pragma unroll
      for (int mf = 0; mf < 8; ++mf)
        #pragma unroll
        for (int nf = 0; nf < 4; ++nf)
          acc[mf][nf] = __builtin_amdgcn_mfma_f32_16x16x32_bf16(af[mf], bfr[nf], acc[mf][nf], 0, 0, 0);
    } else {
      if (t + 1 < 17) buildB(t + 1);
    }
    __syncthreads();
  }

  // ---- epilogue: Q-fold + reduce over row-groups ----
  float s[4] = {0.f, 0.f, 0.f, 0.f};
  const int rg = (lane >> 4) * 4;
  #pragma unroll
  for (int mf = 0; mf < 8; ++mf) {
    #pragma unroll
    for (int reg = 0; reg < 4; ++reg) {
      const int q  = q00 + mf * 16 + rg + reg;   // 0..255 within group
      const int qa = q >> 4, qb = q & 15;
      #pragma unroll
      for (int nf = 0; nf < 4; ++nf) {
        const int p = nf * 16 + (lane & 15);
        s[nf] += acc[mf][nf][reg] * (x_lds[qa][p] * x_lds[qb][p]);
      }
    }
  }
  #pragma unroll
  for (int nf = 0; nf < 4; ++nf) {
    s[nf] += __shfl_xor(s[nf], 16);
    s[nf] += __shfl_xor(s[nf], 32);
  }
  if (lane < 16) {
    #pragma unroll
    for (int nf = 0; nf < 4; ++nf) red[wv][nf * 16 + lane] = s[nf];
  }
  __syncthreads();

  // ---- final combine + U1 terms + store ----
  if (tid < 256) {
    const int slot = tid >> 6;   // 0..2 = 1o w, 3 = 0e
    const int n    = tid & 63;
    const int cc   = ((blk & 1) << 6) + n;
    if (slot < 3) {
      float u1 = 0.f;
      #pragma unroll
      for (int xx = 0; xx < 16; ++xx) u1 += U1_1o[slot * 16 + xx] * x_lds[xx][n];
      out[(size_t)b * 512 + 128 + cc * 3 + slot] =
          red[2 * slot][n] + red[2 * slot + 1][n] + zbuf[Z11][n] * u1;
    } else {
      float u1 = 0.f;
      #pragma unroll
      for (int xx = 0; xx < 16; ++xx) u1 += U1_0e[xx] * x_lds[xx][n];
      out[(size_t)b * 512 + cc] =
          red[6][n] + red[7][n] + zbuf[Z10][n] * u1;
    }
  }
}

// ---- fallback: round-3 scalar kernel (known good), used if ws too small ----
__global__ __launch_bounds__(512, 2) void symcon_fallback(
    const float* __restrict__ x, const float* __restrict__ y,
    const float* __restrict__ U1_0e, const float* __restrict__ U2_0e,
    const float* __restrict__ U3_0e, const float* __restrict__ U1_1o,
    const float* __restrict__ U2_1o, const float* __restrict__ U3_1o,
    const float* __restrict__ w1_0e, const float* __restrict__ w2_0e,
    const float* __restrict__ w3_0e, const float* __restrict__ w1_1o,
    const float* __restrict__ w2_1o, const float* __restrict__ w3_1o,
    float* __restrict__ out)
{
  __shared__ float x_lds[16][64];
  __shared__ float red[8][64];
  const int tid  = threadIdx.x;
  const int lane = tid & 63;
  const int wv   = __builtin_amdgcn_readfirstlane(tid >> 6);
  const int blk  = blockIdx.x;
  const int pair0 = blk * 64;
  const int b    = blk >> 1;
  const int c    = ((blk & 1) << 6) + lane;

  for (int t = tid; t < 16 * 64; t += 512) {
    const int i = t >> 6, n = t & 63;
    x_lds[i][n] = x[(size_t)(pair0 + n) * 16 + i];
  }
  __syncthreads();

  float yv[EE];
  #pragma unroll
  for (int e = 0; e < EE; ++e) yv[e] = y[b * EE + e];

  const int grp  = wv >> 1;
  const int half = wv & 1;
  const int q00  = half * 128;
  float s = 0.f;

  if (grp < 3) {
    float z3[33];
    #pragma unroll
    for (int k = 0; k < 33; ++k) {
      float a = 0.f;
      #pragma unroll
      for (int e = 0; e < EE; ++e) a += w3_1o[(e * 33 + k) * 128 + c] * yv[e];
      z3[k] = a;
    }
    float z2[6];
    #pragma unroll
    for (int k = 0; k < 6; ++k) {
      float a = 0.f;
      #pragma unroll
      for (int e = 0; e < EE; ++e) a += w2_1o[(e * 6 + k) * 128 + c] * yv[e];
      z2[k] = a;
    }
    const float* __restrict__ U3base = U3_1o + ((size_t)grp * 256 + q00) * 528;
    const float* __restrict__ U2base = U2_1o + (grp * 256 + q00) * 6;
    #pragma unroll 1
    for (int rb = 0; rb < 16; ++rb) {
      float acc[8];
      #pragma unroll
      for (int r = 0; r < 8; ++r) acc[r] = 0.f;
      #pragma unroll 2
      for (int i = 0; i < 16; ++i) {
        const float xi = x_lds[i][lane];
        float pj[33];
        #pragma unroll
        for (int k = 0; k < 33; ++k) pj[k] = xi * z3[k];
        const float* __restrict__ Ur = U3base + (size_t)(rb * 8) * 528 + i * 33;
        #pragma unroll
        for (int r = 0; r < 8; ++r)
          #pragma unroll
          for (int k = 0; k < 33; ++k) acc[r] += Ur[r * 528 + k] * pj[k];
      }
      #pragma unroll
      for (int r = 0; r < 8; ++r) {
        const int q = q00 + rb * 8 + r;
        float a2 = acc[r];
        #pragma unroll
        for (int k = 0; k < 6; ++k) a2 += U2base[(rb * 8 + r) * 6 + k] * z2[k];
        s += a2 * (x_lds[q >> 4][lane] * x_lds[q & 15][lane]);
      }
    }
  } else {
    float z3[23];
    #pragma unroll
    for (int k = 0; k < 23; ++k) {
      float a = 0.f;
      #pragma unroll
      for (int e = 0; e < EE; ++e) a += w3_0e[(e * 23 + k) * 128 + c] * yv[e];
      z3[k] = a;
    }
    float z2[4];
    #pragma unroll
    for (int k = 0; k < 4; ++k) {
      float a = 0.f;
      #pragma unroll
      for (int e = 0; e < EE; ++e) a += w2_0e[(e * 4 + k) * 128 + c] * yv[e];
      z2[k] = a;
    }
    const float* __restrict__ U3base = U3_0e + (size_t)q00 * 368;
    const float* __restrict__ U2base = U2_0e + q00 * 4;
    #pragma unroll 1
    for (int rb = 0; rb < 16; ++rb) {
      float acc[8];
      #pragma unroll
      for (int r = 0; r < 8; ++r) acc[r] = 0.f;
      #pragma unroll 2
      for (int i = 0; i < 16; ++i) {
        const float xi = x_lds[i][lane];
        float pj[23];
        #pragma unroll
        for (int k = 0; k < 23; ++k) pj[k] = xi * z3[k];
        const float* __restrict__ Ur = U3base + (size_t)(rb * 8) * 368 + i * 23;
        #pragma unroll
        for (int r = 0; r < 8; ++r)
          #pragma unroll
          for (int k = 0; k < 23; ++k) acc[r] += Ur[r * 368 + k] * pj[k];
      }
      #pragma unroll
      for (int r = 0; r < 8; ++r) {
        const int q = q00 + rb * 8 + r;
        float a2 = acc[r];
        #pragma unroll
        for (int k = 0; k < 4; ++k) a2 += U2base[(rb * 8 + r) * 4 + k] * z2[k];
        s += a2 * (x_lds[q >> 4][lane] * x_lds[q & 15][lane]);
      }
    }
  }

  red[wv][lane] = s;
  __syncthreads();

  if (tid < 256) {
    const int slot = tid >> 6;
    const int n    = tid & 63;
    const int cc   = ((blk & 1) << 6) + n;
    float u1 = 0.f, z1 = 0.f;
    if (slot < 3) {
      #pragma unroll
      for (int xx = 0; xx < 16; ++xx) u1 += U1_1o[slot * 16 + xx] * x_lds[xx][n];
      #pragma unroll
      for (int e = 0; e < EE; ++e) z1 += w1_1o[e * 128 + cc] * y[b * EE + e];
      out[(size_t)b * 512 + 128 + cc * 3 + slot] = red[2 * slot][n] + red[2 * slot + 1][n] + z1 * u1;
    } else {
      #pragma unroll
      for (int xx = 0; xx < 16; ++xx) u1 += U1_0e[xx] * x_lds[xx][n];
      #pragma unroll
      for (int e = 0; e < EE; ++e) z1 += w1_0e[e * 128 + cc] * y[b * EE + e];
      out[(size_t)b * 512 + cc] = red[6][n] + red[7][n] + z1 * u1;
    }
  }
}

extern "C" void kernel_launch(void* const* d_in, const int* in_sizes, int n_in,
                              void* d_out, int out_size, void* d_ws, size_t ws_size,
                              hipStream_t stream) {
  const float* x     = (const float*)d_in[0];
  const float* y     = (const float*)d_in[1];
  const float* U1_0e = (const float*)d_in[2];
  const float* U2_0e = (const float*)d_in[3];
  const float* U3_0e = (const float*)d_in[4];
  const float* U1_1o = (const float*)d_in[5];
  const float* U2_1o = (const float*)d_in[6];
  const float* U3_1o = (const float*)d_in[7];
  const float* w1_0e = (const float*)d_in[8];
  const float* w2_0e = (const float*)d_in[9];
  const float* w3_0e = (const float*)d_in[10];
  const float* w1_1o = (const float*)d_in[11];
  const float* w2_1o = (const float*)d_in[12];
  const float* w3_1o = (const float*)d_in[13];
  (void)in_sizes; (void)n_in; (void)out_size;

  if (ws_size >= WS_NEED) {
    const int prep_blocks = (A1_ELEMS + A0_ELEMS + 255) / 256;
    hipLaunchKernelGGL(prep_kernel, dim3(prep_blocks), dim3(256), 0, stream,
                       U3_1o, U2_1o, U3_0e, U2_0e, (unsigned short*)d_ws);
    hipLaunchKernelGGL(symcon_mfma, dim3(256), dim3(512), 0, stream,
                       x, y, U1_0e, U1_1o, w1_0e, w2_0e, w3_0e,
                       w1_1o, w2_1o, w3_1o, (const unsigned short*)d_ws,
                       (float*)d_out);
  } else {
    hipLaunchKernelGGL(symcon_fallback, dim3(256), dim3(512), 0, stream,
                       x, y, U1_0e, U2_0e, U3_0e, U1_1o, U2_1o, U3_1o,
                       w1_0e, w2_0e, w3_0e, w1_1o, w2_1o, w3_1o,
                       (float*)d_out);
  }
}